// Round 15
// baseline (64.719 us; speedup 1.0000x reference)
//
#include <hip/hip_runtime.h>
#include <stdint.h>

// Problem constants (from reference):
#define T_DIM 1024
#define B_DIM 8
#define C_DIM 1024
#define H_DIM 16
#define K_SZ  7
#define P_PAD 3
#define O_DIM (H_DIM * K_SZ)   // 112
#define TB    (T_DIM * B_DIM)  // 8192 rows

typedef __attribute__((ext_vector_type(8))) short bf16x8;  // 4 VGPRs, 8 bf16
typedef __attribute__((ext_vector_type(4))) float f32x4;

union FragU { uint32_t u[4]; bf16x8 v; };

// RNE fp32->bf16 pack of two floats into one dword (lo=a, hi=b)
__device__ inline uint32_t pk_bf16(float a, float b) {
  uint32_t ua = __float_as_uint(a), ub = __float_as_uint(b);
  ua += 0x7FFFu + ((ua >> 16) & 1u);
  ub += 0x7FFFu + ((ub >> 16) & 1u);
  return (ua >> 16) | (ub & 0xFFFF0000u);
}

__device__ inline bf16x8 load_bf16x8_cvt(const float* __restrict__ p) {
  f32x4 lo = *reinterpret_cast<const f32x4*>(p);
  f32x4 hi = *reinterpret_cast<const f32x4*>(p + 4);
  FragU f;
  f.u[0] = pk_bf16(lo[0], lo[1]);
  f.u[1] = pk_bf16(lo[2], lo[3]);
  f.u[2] = pk_bf16(hi[0], hi[1]);
  f.u[3] = pk_bf16(hi[2], hi[3]);
  return f.v;
}

// Kernel 0: build fragment-native bf16 W.
// Wf[((ks*7)+nf)*64 + lane] (16B) = W[nf*16+(lane&15)][ks*32+(lane>>4)*8 .. +7]
__global__ __launch_bounds__(256) void prep_wfrag_kernel(
    const float* __restrict__ Wl, uint16_t* __restrict__ Wf) {
  const int t  = blockIdx.x * 256 + threadIdx.x;  // 0..14335
  const int f  = t >> 6;
  const int l  = t & 63;
  const int ks = f / 7;
  const int nf = f - ks * 7;
  const int row = nf * 16 + (l & 15);
  const int kb  = ks * 32 + (l >> 4) * 8;
  bf16x8 v = load_bf16x8_cvt(Wl + (size_t)row * C_DIM + kb);
  *reinterpret_cast<bf16x8*>(Wf + (size_t)t * 8) = v;   // coalesced 16B/lane
}

// Kernel 1 -- DIAGNOSTIC 3-PASS build of the round-13 logits kernel.
// Runs the identical body 3 times (passes 2,3 fully cache-warm) so the
// dispatch exceeds the harness's ~40us fill kernels and finally shows up
// in the rocprof top-5 with its own MfmaUtil/VALUBusy/FETCH/Occupancy.
// Numerics identical to a single pass (wbuf rewritten identically).
__global__ __launch_bounds__(512, 4) void logits_kernel(
    const float* __restrict__ x, const uint16_t* __restrict__ Wf,
    const float* __restrict__ bl, float* __restrict__ wbuf) {
  __shared__ float part[8][16][116];   // 59.4KB: per-K-eighth logits
  __shared__ float wsm[16][112];       // 7.2KB: softmax weights

  const int tid  = threadIdx.x;
  const int wv   = tid >> 6;           // 0..7 = K-eighth
  const int lane = tid & 63;
  const int l15  = lane & 15;
  const int oct  = lane >> 4;
  const int rb   = blockIdx.x * 16;

#pragma unroll 1
  for (int pass = 0; pass < 3; ++pass) {
    {
      f32x4 acc[7];
#pragma unroll
      for (int nf = 0; nf < 7; ++nf) acc[nf] = (f32x4)(0.f);

      const float* __restrict__ xr =
          x + (size_t)(rb + l15) * C_DIM + wv * 128 + oct * 8;
#pragma unroll
      for (int s = 0; s < 4; ++s) {
        bf16x8 a = load_bf16x8_cvt(xr + s * 32);
        const int ksg = wv * 4 + s;
#pragma unroll
        for (int nf = 0; nf < 7; ++nf) {
          bf16x8 bf = *reinterpret_cast<const bf16x8*>(
              Wf + ((size_t)((ksg * 7 + nf) * 64) + lane) * 8);
          acc[nf] = __builtin_amdgcn_mfma_f32_16x16x32_bf16(a, bf, acc[nf], 0, 0, 0);
        }
      }
      // D layout: col = lane&15 (W row), row = (lane>>4)*4 + reg (x row)
#pragma unroll
      for (int nf = 0; nf < 7; ++nf)
#pragma unroll
        for (int rr = 0; rr < 4; ++rr)
          part[wv][oct * 4 + rr][nf * 16 + l15] = acc[nf][rr];
    }
    __syncthreads();

    // reduce 8 partials + bias + softmax (16 rows x 16 heads)
    if (tid < 256) {
      const int row = tid >> 4;
      const int h   = tid & 15;
      float lg[7];
      float m = -1e30f;
#pragma unroll
      for (int j = 0; j < 7; ++j) {
        const int c = h * 7 + j;
        float s_ = bl[c];
#pragma unroll
        for (int kh = 0; kh < 8; ++kh) s_ += part[kh][row][c];
        lg[j] = s_;
        m = fmaxf(m, s_);
      }
      float s = 0.f;
#pragma unroll
      for (int j = 0; j < 7; ++j) { lg[j] = __expf(lg[j] - m); s += lg[j]; }
      const float inv = 1.0f / s;
#pragma unroll
      for (int j = 0; j < 7; ++j) wsm[row][h * 7 + j] = lg[j] * inv;
    }
    __syncthreads();

    // coalesced wbuf write: 16 rows x 112 = 448 float4; threads 0..447
    if (tid < 448) {
      const int row = tid / 28;            // 28 float4 per row
      const int c4  = (tid - row * 28) * 4;
      f32x4 v;
      v[0] = wsm[row][c4 + 0];
      v[1] = wsm[row][c4 + 1];
      v[2] = wsm[row][c4 + 2];
      v[3] = wsm[row][c4 + 3];
      *reinterpret_cast<f32x4*>(wbuf + (size_t)(rb + row) * O_DIM + c4) = v;
    }
    __syncthreads();   // pass p+1 part-writes must not race pass p reads
  }
}

// Kernel 2 (round-1 proven, ~10.7us ~= HBM floor):
// out[t,b,c] = sum_j w[t,b,h(c),j] * x[t-3+j, b, c] + bias[c]
__global__ __launch_bounds__(256) void dynconv_kernel(
    const float* __restrict__ x, const float* __restrict__ w,
    const float* __restrict__ bias, float* __restrict__ out) {
  const int row = blockIdx.x;   // t*B + b
  const int t   = row >> 3;
  const int b   = row & 7;
  const int tid = threadIdx.x;
  const int c4  = tid << 2;
  const int h   = c4 >> 6;      // R = 64 channels per head
  const float* __restrict__ wr = w + (size_t)row * O_DIM + h * K_SZ;

  float ax = 0.f, ay = 0.f, az = 0.f, aw = 0.f;
#pragma unroll
  for (int j = 0; j < K_SZ; ++j) {
    int st = t - P_PAD + j;
    if (st < 0 || st >= T_DIM) continue;
    float wj = wr[j];
    const float4 xv = *reinterpret_cast<const float4*>(
        x + ((size_t)(st * B_DIM + b)) * C_DIM + c4);
    ax += wj * xv.x;
    ay += wj * xv.y;
    az += wj * xv.z;
    aw += wj * xv.w;
  }
  float4 bv = *reinterpret_cast<const float4*>(bias + c4);
  float4 o4 = make_float4(ax + bv.x, ay + bv.y, az + bv.z, aw + bv.w);
  *reinterpret_cast<float4*>(out + (size_t)row * C_DIM + c4) = o4;
}

extern "C" void kernel_launch(void* const* d_in, const int* in_sizes, int n_in,
                              void* d_out, int out_size, void* d_ws, size_t ws_size,
                              hipStream_t stream) {
  const float* x  = (const float*)d_in[0];   // (T,B,C)
  const float* Wl = (const float*)d_in[1];   // (H*K, C)
  const float* bl = (const float*)d_in[2];   // (H*K,)
  const float* cb = (const float*)d_in[3];   // (C,)
  float* out = (float*)d_out;                // (T,B,C)

  const size_t WF_BYTES   = 262144;                    // 224KB frag-W, padded
  const size_t WBUF_BYTES = (size_t)TB * O_DIM * 4;    // 3.67 MB
  const bool prepped = ws_size >= WF_BYTES + WBUF_BYTES;

  if (prepped) {
    uint16_t* wf = (uint16_t*)d_ws;
    float* wbuf  = (float*)((char*)d_ws + WF_BYTES);
    prep_wfrag_kernel<<<(32 * 7 * 64) / 256, 256, 0, stream>>>(Wl, wf);
    logits_kernel<<<TB / 16, 512, 0, stream>>>(x, wf, bl, wbuf);
    dynconv_kernel<<<TB, 256, 0, stream>>>(x, wbuf, cb, out);
  } else {
    // BRANCH DETECTOR: if ws_size can't hold Wf+wbuf, skip logits entirely.
    // Output becomes garbage -> huge absmax -> unambiguous signal that all
    // previous two-kernel rounds silently ran the scattered-B fallback.
    float* wbuf = (float*)d_ws;
    dynconv_kernel<<<TB, 256, 0, stream>>>(x, wbuf, cb, out);
  }
}

// Round 16
// 41.126 us; speedup vs baseline: 1.5737x; 1.5737x over previous
//
#include <hip/hip_runtime.h>
#include <stdint.h>

// Problem constants (from reference):
#define T_DIM 1024
#define B_DIM 8
#define C_DIM 1024
#define H_DIM 16
#define K_SZ  7
#define P_PAD 3
#define O_DIM (H_DIM * K_SZ)   // 112
#define TB    (T_DIM * B_DIM)  // 8192 rows

typedef __attribute__((ext_vector_type(8))) short bf16x8;  // 4 VGPRs, 8 bf16
typedef __attribute__((ext_vector_type(4))) float f32x4;

union FragU { uint32_t u[4]; bf16x8 v; };

// RNE fp32->bf16 pack of two floats into one dword (lo=a, hi=b)
__device__ inline uint32_t pk_bf16(float a, float b) {
  uint32_t ua = __float_as_uint(a), ub = __float_as_uint(b);
  ua += 0x7FFFu + ((ua >> 16) & 1u);
  ub += 0x7FFFu + ((ub >> 16) & 1u);
  return (ua >> 16) | (ub & 0xFFFF0000u);
}

__device__ inline bf16x8 load_bf16x8_cvt(const float* __restrict__ p) {
  f32x4 lo = *reinterpret_cast<const f32x4*>(p);
  f32x4 hi = *reinterpret_cast<const f32x4*>(p + 4);
  FragU f;
  f.u[0] = pk_bf16(lo[0], lo[1]);
  f.u[1] = pk_bf16(lo[2], lo[3]);
  f.u[2] = pk_bf16(hi[0], hi[1]);
  f.u[3] = pk_bf16(hi[2], hi[3]);
  return f.v;
}

// Kernel 0: build fragment-native bf16 W.
// Wf[((ks*7)+nf)*64 + lane] (16B) = W[nf*16+(lane&15)][ks*32+(lane>>4)*8 .. +7]
__global__ __launch_bounds__(256) void prep_wfrag_kernel(
    const float* __restrict__ Wl, uint16_t* __restrict__ Wf) {
  const int t  = blockIdx.x * 256 + threadIdx.x;  // 0..14335
  const int f  = t >> 6;
  const int l  = t & 63;
  const int ks = f / 7;
  const int nf = f - ks * 7;
  const int row = nf * 16 + (l & 15);
  const int kb  = ks * 32 + (l >> 4) * 8;
  bf16x8 v = load_bf16x8_cvt(Wl + (size_t)row * C_DIM + kb);
  *reinterpret_cast<bf16x8*>(Wf + (size_t)t * 8) = v;   // coalesced 16B/lane
}

// Kernel 1: w = softmax_K( x @ W^T + b ).
// 512 blocks x 512 threads, 2 blocks/CU. KEY CHANGE (r15 counters):
// amdgpu_waves_per_eu(4,4) pins exactly 4 waves/SIMD (16 waves/CU) and
// raises the VGPR budget 64 -> 128. r15 diagnosed: default allocation of
// 64 VGPRs caused scratch spills (4.7x write amplification, 12MB/pass
// warm re-fetch) and ~2 loads in flight (all pipes <6% busy). With 128
// VGPRs the acc[7] + ~12 outstanding loads fit with no spill.
template <bool PREPPED>
__global__ __launch_bounds__(512)
__attribute__((amdgpu_waves_per_eu(4, 4)))
void logits_kernel(
    const float* __restrict__ x, const float* __restrict__ Wl,
    const uint16_t* __restrict__ Wf, const float* __restrict__ bl,
    float* __restrict__ wbuf) {
  __shared__ float part[8][16][116];   // 59.4KB: per-K-eighth logits
  __shared__ float wsm[16][112];       // 7.2KB: softmax weights

  const int tid  = threadIdx.x;
  const int wv   = tid >> 6;           // 0..7 = K-eighth
  const int lane = tid & 63;
  const int l15  = lane & 15;
  const int oct  = lane >> 4;
  const int rb   = blockIdx.x * 16;

  {
    f32x4 acc[7];
#pragma unroll
    for (int nf = 0; nf < 7; ++nf) acc[nf] = (f32x4)(0.f);

    const float* __restrict__ xr =
        x + (size_t)(rb + l15) * C_DIM + wv * 128 + oct * 8;
#pragma unroll
    for (int s = 0; s < 4; ++s) {
      bf16x8 a = load_bf16x8_cvt(xr + s * 32);
      const int ksg = wv * 4 + s;
#pragma unroll
      for (int nf = 0; nf < 7; ++nf) {
        bf16x8 bf;
        if (PREPPED)
          bf = *reinterpret_cast<const bf16x8*>(
              Wf + ((size_t)((ksg * 7 + nf) * 64) + lane) * 8);
        else
          bf = load_bf16x8_cvt(
              Wl + (size_t)(nf * 16 + l15) * C_DIM + ksg * 32 + oct * 8);
        acc[nf] = __builtin_amdgcn_mfma_f32_16x16x32_bf16(a, bf, acc[nf], 0, 0, 0);
      }
    }
    // D layout: col = lane&15 (W row), row = (lane>>4)*4 + reg (x row)
#pragma unroll
    for (int nf = 0; nf < 7; ++nf)
#pragma unroll
      for (int rr = 0; rr < 4; ++rr)
        part[wv][oct * 4 + rr][nf * 16 + l15] = acc[nf][rr];
  }
  __syncthreads();

  // reduce 8 partials + bias + softmax (16 rows x 16 heads)
  if (tid < 256) {
    const int row = tid >> 4;
    const int h   = tid & 15;
    float lg[7];
    float m = -1e30f;
#pragma unroll
    for (int j = 0; j < 7; ++j) {
      const int c = h * 7 + j;
      float s_ = bl[c];
#pragma unroll
      for (int kh = 0; kh < 8; ++kh) s_ += part[kh][row][c];
      lg[j] = s_;
      m = fmaxf(m, s_);
    }
    float s = 0.f;
#pragma unroll
    for (int j = 0; j < 7; ++j) { lg[j] = __expf(lg[j] - m); s += lg[j]; }
    const float inv = 1.0f / s;
#pragma unroll
    for (int j = 0; j < 7; ++j) wsm[row][h * 7 + j] = lg[j] * inv;
  }
  __syncthreads();

  // coalesced wbuf write: 16 rows x 112 = 448 float4; threads 0..447
  if (tid < 448) {
    const int row = tid / 28;            // 28 float4 per row
    const int c4  = (tid - row * 28) * 4;
    f32x4 v;
    v[0] = wsm[row][c4 + 0];
    v[1] = wsm[row][c4 + 1];
    v[2] = wsm[row][c4 + 2];
    v[3] = wsm[row][c4 + 3];
    *reinterpret_cast<f32x4*>(wbuf + (size_t)(rb + row) * O_DIM + c4) = v;
  }
}

// Kernel 2 (round-1 proven, ~10.7us ~= HBM floor):
// out[t,b,c] = sum_j w[t,b,h(c),j] * x[t-3+j, b, c] + bias[c]
__global__ __launch_bounds__(256) void dynconv_kernel(
    const float* __restrict__ x, const float* __restrict__ w,
    const float* __restrict__ bias, float* __restrict__ out) {
  const int row = blockIdx.x;   // t*B + b
  const int t   = row >> 3;
  const int b   = row & 7;
  const int tid = threadIdx.x;
  const int c4  = tid << 2;
  const int h   = c4 >> 6;      // R = 64 channels per head
  const float* __restrict__ wr = w + (size_t)row * O_DIM + h * K_SZ;

  float ax = 0.f, ay = 0.f, az = 0.f, aw = 0.f;
#pragma unroll
  for (int j = 0; j < K_SZ; ++j) {
    int st = t - P_PAD + j;
    if (st < 0 || st >= T_DIM) continue;
    float wj = wr[j];
    const float4 xv = *reinterpret_cast<const float4*>(
        x + ((size_t)(st * B_DIM + b)) * C_DIM + c4);
    ax += wj * xv.x;
    ay += wj * xv.y;
    az += wj * xv.z;
    aw += wj * xv.w;
  }
  float4 bv = *reinterpret_cast<const float4*>(bias + c4);
  float4 o4 = make_float4(ax + bv.x, ay + bv.y, az + bv.z, aw + bv.w);
  *reinterpret_cast<float4*>(out + (size_t)row * C_DIM + c4) = o4;
}

extern "C" void kernel_launch(void* const* d_in, const int* in_sizes, int n_in,
                              void* d_out, int out_size, void* d_ws, size_t ws_size,
                              hipStream_t stream) {
  const float* x  = (const float*)d_in[0];   // (T,B,C)
  const float* Wl = (const float*)d_in[1];   // (H*K, C)
  const float* bl = (const float*)d_in[2];   // (H*K,)
  const float* cb = (const float*)d_in[3];   // (C,)
  float* out = (float*)d_out;                // (T,B,C)

  const size_t WF_BYTES   = 262144;                    // 224KB frag-W, padded
  const size_t WBUF_BYTES = (size_t)TB * O_DIM * 4;    // 3.67 MB
  const bool prepped = ws_size >= WF_BYTES + WBUF_BYTES;

  if (prepped) {
    uint16_t* wf = (uint16_t*)d_ws;
    float* wbuf  = (float*)((char*)d_ws + WF_BYTES);
    prep_wfrag_kernel<<<(32 * 7 * 64) / 256, 256, 0, stream>>>(Wl, wf);
    logits_kernel<true><<<TB / 16, 512, 0, stream>>>(x, Wl, wf, bl, wbuf);
    dynconv_kernel<<<TB, 256, 0, stream>>>(x, wbuf, cb, out);
  } else {
    float* wbuf = (float*)d_ws;
    logits_kernel<false><<<TB / 16, 512, 0, stream>>>(x, Wl, nullptr, bl, wbuf);
    dynconv_kernel<<<TB, 256, 0, stream>>>(x, wbuf, cb, out);
  }
}